// Round 1
// baseline (356.813 us; speedup 1.0000x reference)
//
#include <hip/hip_runtime.h>

#define NJ 17
#define RPB 15          // rows per block
#define TPB 256

// joints
#define LSJ 5
#define RSJ 6
#define LHJ 11
#define RHJ 12

__device__ __forceinline__ void norm_row(const float* __restrict__ r,
                                         float* __restrict__ ox,
                                         float* __restrict__ oy) {
    // r: 17 * (x,y,conf)
    float sc0 = r[LSJ*3+2], sc1 = r[RSJ*3+2];
    float hc0 = r[LHJ*3+2], hc1 = r[RHJ*3+2];
    bool ut = ((sc0 > 0.f) || (sc1 > 0.f)) && ((hc0 > 0.f) || (hc1 > 0.f));

    float wl = sc0 > 0.f ? 1.f : 0.f;
    float wr = sc1 > 0.f ? 1.f : 0.f;
    float ws = fmaxf(wl + wr, 1.f);
    float smx = (wl * r[LSJ*3+0] + wr * r[RSJ*3+0]) / ws;
    float smy = (wl * r[LSJ*3+1] + wr * r[RSJ*3+1]) / ws;

    wl = hc0 > 0.f ? 1.f : 0.f;
    wr = hc1 > 0.f ? 1.f : 0.f;
    ws = fmaxf(wl + wr, 1.f);
    float hmx = (wl * r[LHJ*3+0] + wr * r[RHJ*3+0]) / ws;
    float hmy = (wl * r[LHJ*3+1] + wr * r[RHJ*3+1]) / ws;

    if (!ut) { smx = 0.f; smy = 0.f; hmx = 0.f; hmy = 0.f; }

    float cx = (smx + hmx) * 0.5f;
    float cy = (smy + hmy) * 0.5f;
    float dx = smx - hmx, dy = smy - hmy;
    float hh = sqrtf(dx * dx + dy * dy);
    bool valid = ut && (hh >= 10.0f);

    float mnx = r[0], mxx = r[0], mny = r[1], mxy = r[1];
    #pragma unroll
    for (int j = 1; j < NJ; ++j) {
        float x = r[j*3], y = r[j*3+1];
        mnx = fminf(mnx, x); mxx = fmaxf(mxx, x);
        mny = fminf(mny, y); mxy = fmaxf(mxy, y);
    }

    float ih  = 1.f / (hh + 1e-6f);
    float ibx = 1.f / (mxx - mnx + 1e-6f);
    float iby = 1.f / (mxy - mny + 1e-6f);

    #pragma unroll
    for (int j = 0; j < NJ; ++j) {
        float x = r[j*3], y = r[j*3+1];
        float tx = (x - cx) * ih, ty = (y - cy) * ih;
        float bx = (x - mnx) * ibx, by = (y - mny) * iby;
        float nx = valid ? tx : bx;
        float ny = valid ? ty : by;
        ox[j] = fminf(fmaxf(nx, -5.f), 5.f);
        oy[j] = fminf(fmaxf(ny, -5.f), 5.f);
    }
}

__global__ __launch_bounds__(TPB, 2) void jfe_kernel(
    const float* __restrict__ kp, const float* __restrict__ pkp,
    const float* __restrict__ emb,                                    // 17x16
    const float* __restrict__ posW, const float* __restrict__ posB,   // 2x16, 16
    const float* __restrict__ velW, const float* __restrict__ velB,   // 2x8, 8
    const float* __restrict__ angB,                                   // 8
    const float* __restrict__ relW, const float* __restrict__ relB,   // 2x8, 8
    const float* __restrict__ confW, const float* __restrict__ confB, // 1x4, 4
    const float* __restrict__ P1, const float* __restrict__ p1b,      // 60x128, 128
    const float* __restrict__ g1, const float* __restrict__ b1,       // 128,128
    const float* __restrict__ W2, const float* __restrict__ p2b,      // 128x64, 64
    const float* __restrict__ g2, const float* __restrict__ b2,       // 64,64
    float* __restrict__ out, int B)
{
    __shared__ float4 sPA0[32], sPA1[32], sPV0[32], sPV1[32],
                      sPR0[32], sPR1[32], sPC[32];
    __shared__ float  sBase[128];
    __shared__ __align__(16) float sK0[NJ * 132];
    __shared__ float sPx[RPB][NJ], sPy[RPB][NJ], sCf[RPB][NJ];
    __shared__ float sQx[RPB][NJ], sQy[RPB][NJ];
    __shared__ float sTcx[RPB], sTcy[RPB];
    __shared__ float raw[RPB * NJ * 3];

    const int tid  = threadIdx.x;
    const int row0 = blockIdx.x * RPB;
    const int nrows = min(RPB, B - row0);
    const int nld = nrows * NJ * 3;

    // cooperative stage of raw keypoints
    for (int i = tid; i < nld; i += TPB) raw[i] = kp[row0 * 51 + i];

    // fold layer-1 weights (threads 0..127)
    if (tid < 128) {
        const int n = tid;
        float pa0 = 0.f, pa1 = 0.f;
        #pragma unroll
        for (int i = 0; i < 16; ++i) {
            float w = P1[(16 + i) * 128 + n];
            pa0 += posW[i] * w; pa1 += posW[16 + i] * w;
        }
        float pv0 = 0.f, pv1 = 0.f;
        #pragma unroll
        for (int i = 0; i < 8; ++i) {
            float w = P1[(32 + i) * 128 + n];
            pv0 += velW[i] * w; pv1 += velW[8 + i] * w;
        }
        float pr0 = 0.f, pr1 = 0.f;
        #pragma unroll
        for (int i = 0; i < 8; ++i) {
            float w = P1[(48 + i) * 128 + n];
            pr0 += relW[i] * w; pr1 += relW[8 + i] * w;
        }
        float pc = 0.f;
        #pragma unroll
        for (int i = 0; i < 4; ++i) pc += confW[i] * P1[(56 + i) * 128 + n];

        float base = p1b[n];
        #pragma unroll
        for (int i = 0; i < 16; ++i) base += posB[i]  * P1[(16 + i) * 128 + n];
        #pragma unroll
        for (int i = 0; i < 8; ++i)  base += velB[i]  * P1[(32 + i) * 128 + n];
        #pragma unroll
        for (int i = 0; i < 8; ++i)  base += angB[i]  * P1[(40 + i) * 128 + n];
        #pragma unroll
        for (int i = 0; i < 8; ++i)  base += relB[i]  * P1[(48 + i) * 128 + n];
        #pragma unroll
        for (int i = 0; i < 4; ++i)  base += confB[i] * P1[(56 + i) * 128 + n];

        ((float*)sPA0)[n] = pa0; ((float*)sPA1)[n] = pa1;
        ((float*)sPV0)[n] = pv0; ((float*)sPV1)[n] = pv1;
        ((float*)sPR0)[n] = pr0; ((float*)sPR1)[n] = pr1;
        ((float*)sPC)[n]  = pc;  sBase[n] = base;
    }
    __syncthreads();

    // per-row normalization of current keypoints
    if (tid < nrows) {
        norm_row(&raw[tid * 51], &sPx[tid][0], &sPy[tid][0]);
        #pragma unroll
        for (int j = 0; j < NJ; ++j) sCf[tid][j] = raw[tid * 51 + j * 3 + 2];
        sTcx[tid] = 0.25f * (sPx[tid][LSJ] + sPx[tid][RSJ] + sPx[tid][LHJ] + sPx[tid][RHJ]);
        sTcy[tid] = 0.25f * (sPy[tid][LSJ] + sPy[tid][RSJ] + sPy[tid][LHJ] + sPy[tid][RHJ]);
    }

    // fill per-joint constants K0[j][n] (all threads)
    for (int idx = tid; idx < NJ * 128; idx += TPB) {
        int j = idx >> 7, n = idx & 127;
        float v = sBase[n];
        #pragma unroll
        for (int t = 0; t < 16; ++t) v += emb[j * 16 + t] * P1[t * 128 + n];
        sK0[j * 132 + n] = v;
    }
    __syncthreads();

    // restage raw with prev keypoints
    for (int i = tid; i < nld; i += TPB) raw[i] = pkp[row0 * 51 + i];
    __syncthreads();

    if (tid < nrows) {
        norm_row(&raw[tid * 51], &sQx[tid][0], &sQy[tid][0]);
    }
    __syncthreads();

    // ---- phase B: one thread per token ----
    const int r = tid / NJ;
    const int j = tid - r * NJ;
    if (tid < RPB * NJ && r < nrows) {
        const int row = row0 + r;
        float px = sPx[r][j], py = sPy[r][j], cf = sCf[r][j];
        float vx = px - sQx[r][j], vy = py - sQy[r][j];
        float rx = px - sTcx[r],  ry = py - sTcy[r];

        float h[128];
        const float4* k0p = (const float4*)&sK0[j * 132];
        #pragma unroll
        for (int c = 0; c < 32; ++c) {
            float4 a = k0p[c];
            float4 w;
            w = sPA0[c]; a.x += px * w.x; a.y += px * w.y; a.z += px * w.z; a.w += px * w.w;
            w = sPA1[c]; a.x += py * w.x; a.y += py * w.y; a.z += py * w.z; a.w += py * w.w;
            w = sPV0[c]; a.x += vx * w.x; a.y += vx * w.y; a.z += vx * w.z; a.w += vx * w.w;
            w = sPV1[c]; a.x += vy * w.x; a.y += vy * w.y; a.z += vy * w.z; a.w += vy * w.w;
            w = sPR0[c]; a.x += rx * w.x; a.y += rx * w.y; a.z += rx * w.z; a.w += rx * w.w;
            w = sPR1[c]; a.x += ry * w.x; a.y += ry * w.y; a.z += ry * w.z; a.w += ry * w.w;
            w = sPC[c];  a.x += cf * w.x; a.y += cf * w.y; a.z += cf * w.z; a.w += cf * w.w;
            h[4*c+0] = a.x; h[4*c+1] = a.y; h[4*c+2] = a.z; h[4*c+3] = a.w;
        }

        // LN1 + ReLU (register-resident)
        float s = 0.f;
        #pragma unroll
        for (int i = 0; i < 128; ++i) s += h[i];
        float mu = s * (1.f / 128.f);
        float var = 0.f;
        #pragma unroll
        for (int i = 0; i < 128; ++i) { float d = h[i] - mu; var += d * d; }
        var *= (1.f / 128.f);
        float inv = rsqrtf(var + 1e-5f);
        #pragma unroll
        for (int i = 0; i < 128; ++i) {
            float t = (h[i] - mu) * inv * g1[i] + b1[i];
            h[i] = fmaxf(t, 0.f);
        }

        // matmul2: 128 -> 64, weights via uniform (scalar) loads
        float4 o[16];
        #pragma unroll
        for (int m4 = 0; m4 < 16; ++m4) o[m4] = ((const float4*)p2b)[m4];
        #pragma unroll
        for (int k = 0; k < 128; ++k) {
            float hk = h[k];
            #pragma unroll
            for (int m4 = 0; m4 < 16; ++m4) {
                float4 w = ((const float4*)W2)[k * 16 + m4];
                o[m4].x += hk * w.x; o[m4].y += hk * w.y;
                o[m4].z += hk * w.z; o[m4].w += hk * w.w;
            }
        }

        // LN2
        float s2 = 0.f;
        #pragma unroll
        for (int m4 = 0; m4 < 16; ++m4) s2 += o[m4].x + o[m4].y + o[m4].z + o[m4].w;
        float mu2 = s2 * (1.f / 64.f);
        float var2 = 0.f;
        #pragma unroll
        for (int m4 = 0; m4 < 16; ++m4) {
            float d;
            d = o[m4].x - mu2; var2 += d * d;
            d = o[m4].y - mu2; var2 += d * d;
            d = o[m4].z - mu2; var2 += d * d;
            d = o[m4].w - mu2; var2 += d * d;
        }
        var2 *= (1.f / 64.f);
        float inv2 = rsqrtf(var2 + 1e-5f);

        float4* op = (float4*)(out + (((size_t)row) * NJ + j) * 64);
        #pragma unroll
        for (int m4 = 0; m4 < 16; ++m4) {
            float4 t;
            t.x = (o[m4].x - mu2) * inv2 * g2[4*m4+0] + b2[4*m4+0];
            t.y = (o[m4].y - mu2) * inv2 * g2[4*m4+1] + b2[4*m4+1];
            t.z = (o[m4].z - mu2) * inv2 * g2[4*m4+2] + b2[4*m4+2];
            t.w = (o[m4].w - mu2) * inv2 * g2[4*m4+3] + b2[4*m4+3];
            op[m4] = t;
        }
    }
}

extern "C" void kernel_launch(void* const* d_in, const int* in_sizes, int n_in,
                              void* d_out, int out_size, void* d_ws, size_t ws_size,
                              hipStream_t stream) {
    const float* kp    = (const float*)d_in[0];
    const float* pkp   = (const float*)d_in[1];
    const float* emb   = (const float*)d_in[2];
    const float* posW  = (const float*)d_in[3];
    const float* posB  = (const float*)d_in[4];
    const float* velW  = (const float*)d_in[5];
    const float* velB  = (const float*)d_in[6];
    // d_in[7] = angvel_W (unused by reference)
    const float* angB  = (const float*)d_in[8];
    const float* relW  = (const float*)d_in[9];
    const float* relB  = (const float*)d_in[10];
    const float* confW = (const float*)d_in[11];
    const float* confB = (const float*)d_in[12];
    const float* P1    = (const float*)d_in[13];
    const float* p1b   = (const float*)d_in[14];
    const float* g1    = (const float*)d_in[15];
    const float* b1    = (const float*)d_in[16];
    const float* W2    = (const float*)d_in[17];
    const float* p2b   = (const float*)d_in[18];
    const float* g2    = (const float*)d_in[19];
    const float* b2    = (const float*)d_in[20];
    float* out = (float*)d_out;

    int B = in_sizes[0] / (NJ * 3);
    int nblocks = (B + RPB - 1) / RPB;
    jfe_kernel<<<nblocks, TPB, 0, stream>>>(
        kp, pkp, emb, posW, posB, velW, velB, angB, relW, relB,
        confW, confB, P1, p1b, g1, b1, W2, p2b, g2, b2, out, B);
}